// Round 5
// baseline (209.965 us; speedup 1.0000x reference)
//
#include <hip/hip_runtime.h>

#define NB     64
#define CCH    256
#define HW     20480       // 128*160
#define TPB    512         // px per block = 4 tiles x 128
#define NTILE  4
#define GRID_MS 1280       // 32 groups x 40 pranges

// Workspace layout (bytes):
//   sums [2 replicas][2 tensors][64][256] f32 = 262144, zeroed
//   counts [65] i32 @ 262144
//   acc f32 @ 262404 ; ticket u32 @ 262408 ; memset [0, 262412)
//   pS aliases replica1/tensor0 = ws+131072 ; pT = ws+196608
#define WS_COUNTS 262144
#define WS_ACC    262404
#define WS_TICKET 262408
#define WS_ZERO   262412
#define REP_STRIDE (2 * NB * CCH)   // floats per replica
#define WS_PS     131072
#define WS_PT     196608

typedef __attribute__((ext_vector_type(8))) short short8;
typedef __attribute__((ext_vector_type(4))) float f32x4;

#define STRIDE 136   // shorts per LDS row (128 + 8 pad); 272 B = 17*16 -> rows 16B-aligned

// ---------------------------------------------------------------------------
// Main: segment-sum as one-hot MFMA, bf16-RNE single term (no lo residual).
// Block: (tensor, n, 64-ch slice, 512-px range). 1280 blocks, 18 KB LDS.
// Layouts (R3/R4-verified): A: m=lane&15,k=q*8+j; B: n=lane&15,k=q*8+j;
// D: col=lane&15, row=q*4+reg.
__global__ __launch_bounds__(256, 8)
void k_msum(const float* __restrict__ predsS,
            const float* __restrict__ predsT,
            const float* __restrict__ depth,
            float* __restrict__ sums,
            int* __restrict__ counts) {
    int tid = threadIdx.x;
    int blk = blockIdx.x;            // 0..1279
    int prange = blk % 40;
    int group  = blk / 40;           // 0..31
    int tensor = group >> 4;
    int n  = (group >> 2) & 3;
    int cs = group & 3;
    int px0 = prange * TPB;

    const float* xbase = (tensor ? predsT : predsS)
                       + (size_t)(n * CCH + cs * 64) * HW + px0;
    const float* dbase = depth + n * HW + px0;

    __shared__ short sHi[64][STRIDE];
    __shared__ unsigned char sBin[TPB];
    __shared__ int lhist[NB + 1];

    bool desig = (tensor == 0) && (cs == 0);   // 320 blocks cover depth once
    if (desig && tid < NB + 1) lhist[tid] = 0;
    __syncthreads();

    for (int i = tid; i < TPB; i += 256) {
        float f = dbase[i] * 64.0f;
        int b;
        if (!(f >= 0.0f) || f > 64.0f) b = NB;   // NaN via !(f>=0)
        else b = (int)f;                          // f==64.0 -> 64 (matches ref)
        sBin[i] = (unsigned char)b;
        if (desig) atomicAdd(&lhist[b], 1);
    }

    int lane = tid & 63;
    int wv = tid >> 6;
    int l15 = lane & 15;
    int q = lane >> 4;
    int r0 = tid >> 5;               // 0..7
    int c0 = tid & 31;               // float4 column

    f32x4 acc[4];
    #pragma unroll
    for (int mt = 0; mt < 4; ++mt) acc[mt] = (f32x4)0.0f;

    for (int tt = 0; tt < NTILE; ++tt) {
        int t0 = tt * 128;
        float4 vv[8];
        #pragma unroll
        for (int rr = 0; rr < 8; ++rr)
            vv[rr] = *(const float4*)(xbase + (size_t)(rr * 8 + r0) * HW + t0 + c0 * 4);
        __syncthreads();             // sBin ready (first iter) / prev MFMA done
        #pragma unroll
        for (int rr = 0; rr < 8; ++rr) {
            unsigned u0 = __float_as_uint(vv[rr].x), u1 = __float_as_uint(vv[rr].y);
            unsigned u2 = __float_as_uint(vv[rr].z), u3 = __float_as_uint(vv[rr].w);
            uint2 hv;                // bf16 round-half-up (unbiased to 2^-24)
            hv.x = ((u0 + 0x8000u) >> 16) | ((u1 + 0x8000u) & 0xFFFF0000u);
            hv.y = ((u2 + 0x8000u) >> 16) | ((u3 + 0x8000u) & 0xFFFF0000u);
            *(uint2*)&sHi[rr * 8 + r0][c0 * 4] = hv;
        }
        __syncthreads();
        #pragma unroll
        for (int ks = 0; ks < 4; ++ks) {
            unsigned long long bv = *(const unsigned long long*)&sBin[t0 + ks * 32 + q * 8];
            short8 bHi = *(const short8*)&sHi[wv * 16 + l15][ks * 32 + q * 8];
            #pragma unroll
            for (int mt = 0; mt < 4; ++mt) {
                int tgt = mt * 16 + l15;
                short8 afr;
                #pragma unroll
                for (int j = 0; j < 8; ++j)
                    afr[j] = ((int)((bv >> (8 * j)) & 0xFFull) == tgt) ? (short)0x3F80 : (short)0;
                acc[mt] = __builtin_amdgcn_mfma_f32_16x16x32_bf16(afr, bHi, acc[mt], 0, 0, 0);
            }
        }
    }
    // flush into replica (blk&1): halves L2 atomic-line contention
    float* dst = sums + (size_t)(blk & 1) * REP_STRIDE
               + (size_t)tensor * NB * CCH + cs * 64 + wv * 16 + l15;
    #pragma unroll
    for (int mt = 0; mt < 4; ++mt)
        #pragma unroll
        for (int r = 0; r < 4; ++r)
            atomicAdd(&dst[(mt * 16 + q * 4 + r) * CCH], acc[mt][r]);
    if (desig) {
        __syncthreads();
        if (tid < NB + 1 && lhist[tid] != 0) atomicAdd(&counts[tid], lhist[tid]);
    }
}

// ---------------------------------------------------------------------------
// Protos: 64 blocks x 256 threads. Folds the 2 sums replicas, normalizes.
// pS/pT alias replica 1 — each thread reads its own addresses before writing.
__global__ __launch_bounds__(256) void k_protos(const float* __restrict__ sums,
                                                const int* __restrict__ counts,
                                                float* __restrict__ pS,
                                                float* __restrict__ pT) {
    int b = blockIdx.x, t = threadIdx.x;
    int ci = counts[b];
    float cnt = (float)(ci < 1 ? 1 : ci);
    float mS = (sums[b * CCH + t] + sums[REP_STRIDE + b * CCH + t]) / cnt;
    float mT = (sums[(NB + b) * CCH + t] + sums[REP_STRIDE + (NB + b) * CCH + t]) / cnt;
    float ss = mS * mS, st = mT * mT;
    #pragma unroll
    for (int o = 32; o; o >>= 1) {
        ss += __shfl_xor(ss, o, 64);
        st += __shfl_xor(st, o, 64);
    }
    __shared__ float rs[4], rt[4];
    int w = t >> 6;
    if ((t & 63) == 0) { rs[w] = ss; rt[w] = st; }
    __syncthreads();
    float nS = sqrtf(rs[0] + rs[1] + rs[2] + rs[3]);
    float nT = sqrtf(rt[0] + rt[1] + rt[2] + rt[3]);
    pS[b * CCH + t] = mS / fmaxf(nS, 1e-12f);
    pT[b * CCH + t] = mT / fmaxf(nT, 1e-12f);
}

// ---------------------------------------------------------------------------
// Sims + loss: 64 blocks (row i) x 256 threads. Ticketed final write.
__global__ __launch_bounds__(256) void k_sim(const float* __restrict__ pS,
                                             const float* __restrict__ pT,
                                             float* __restrict__ acc,
                                             unsigned int* __restrict__ ticket,
                                             float* __restrict__ out) {
    int i = blockIdx.x;
    int t = threadIdx.x;
    int j = t & 63, seg = t >> 6;
    __shared__ float rowS[CCH], rowT[CCH];
    rowS[t] = pS[i * CCH + t];
    rowT[t] = pT[i * CCH + t];
    __syncthreads();
    const float4* Sj = (const float4*)(pS + j * CCH + seg * 64);
    const float4* Tj = (const float4*)(pT + j * CCH + seg * 64);
    const float4* Si = (const float4*)(rowS + seg * 64);
    const float4* Ti = (const float4*)(rowT + seg * 64);
    float dS = 0.0f, dT = 0.0f;
    #pragma unroll
    for (int k = 0; k < 16; ++k) {
        float4 a = Si[k], b = Sj[k];
        dS += a.x * b.x + a.y * b.y + a.z * b.z + a.w * b.w;
        float4 c = Ti[k], d = Tj[k];
        dT += c.x * d.x + c.y * d.y + c.z * d.z + c.w * d.w;
    }
    __shared__ float sS[4][64], sT[4][64];
    sS[seg][j] = dS;
    sT[seg][j] = dT;
    __syncthreads();
    if (t < 64) {
        float fS = sS[0][t] + sS[1][t] + sS[2][t] + sS[3][t];
        float fT = sT[0][t] + sT[1][t] + sT[2][t] + sT[3][t];
        float e = fS - fT;
        e = e * e;
        #pragma unroll
        for (int o = 32; o; o >>= 1) e += __shfl_xor(e, o, 64);
        if (t == 0) {
            atomicAdd(acc, e);
            __threadfence();
            unsigned int r = atomicAdd(ticket, 1u);
            if (r == NB - 1) {
                float tot = atomicAdd(acc, 0.0f);   // device-scope read
                out[0] = tot * (1.0f / (float)(NB * NB));
            }
        }
    }
}

extern "C" void kernel_launch(void* const* d_in, const int* in_sizes, int n_in,
                              void* d_out, int out_size, void* d_ws, size_t ws_size,
                              hipStream_t stream) {
    const float* predsS = (const float*)d_in[0];
    const float* predsT = (const float*)d_in[1];
    const float* depth  = (const float*)d_in[2];
    char* ws = (char*)d_ws;
    float* sums = (float*)ws;
    int* counts = (int*)(ws + WS_COUNTS);
    float* acc = (float*)(ws + WS_ACC);
    unsigned int* ticket = (unsigned int*)(ws + WS_TICKET);
    float* pS = (float*)(ws + WS_PS);
    float* pT = (float*)(ws + WS_PT);

    hipMemsetAsync(ws, 0, WS_ZERO, stream);
    k_msum<<<GRID_MS, 256, 0, stream>>>(predsS, predsT, depth, sums, counts);
    k_protos<<<NB, 256, 0, stream>>>(sums, counts, pS, pT);
    k_sim<<<NB, 256, 0, stream>>>(pS, pT, acc, ticket, (float*)d_out);
}

// Round 6
// 202.663 us; speedup vs baseline: 1.0360x; 1.0360x over previous
//
#include <hip/hip_runtime.h>

#define NB     64
#define CCH    256
#define HW     20480       // 128*160
#define PXB    1024        // px per block
#define NPR    (HW/PXB)    // 20 pixel ranges
#define GRID_MS (2*4*16*NPR)   // 2560 blocks

// Workspace layout (bytes):
//   sums [2 replicas][2 tensors][64][256] f32 = 262144, zeroed
//   counts [65] i32 @ 262144 ; acc @ 262404 ; ticket @ 262408 ; memset [0,262412)
//   pS aliases replica1/tensor0 = ws+131072 ; pT = ws+196608 (R5-verified safe)
#define REP_STRIDE (2 * NB * CCH)
#define WS_COUNTS 262144
#define WS_ACC    262404
#define WS_TICKET 262408
#define WS_ZERO   262412
#define WS_PS     131072
#define WS_PT     196608

typedef __attribute__((ext_vector_type(8))) short short8;
typedef __attribute__((ext_vector_type(4))) float f32x4;

#define ROWSTR 520   // shorts per LDS row (512+8 pad); 1040 B = 65*16 -> 16B-aligned rows

// ---------------------------------------------------------------------------
// Main: segment-sum as one-hot MFMA. DRAM-friendly: every wave-load is a
// full-wave 1 KB contiguous segment; 4 KB contiguous per channel-row visit.
// Block: (tensor, n, 16-ch group, 1024-px range). Wave = 4 rows (staging)
// and one 128-px k-chunk (MFMA). Layouts (R3-R5 verified):
//   A: m=lane&15,k=q*8+j; B: n=lane&15,k=q*8+j; D: col=lane&15,row=q*4+reg.
__global__ __launch_bounds__(256, 6)
void k_msum(const float* __restrict__ predsS,
            const float* __restrict__ predsT,
            const float* __restrict__ depth,
            float* __restrict__ sums,
            int* __restrict__ counts) {
    int tid = threadIdx.x;
    int blk = blockIdx.x;
    int prange = blk % NPR;
    int group  = blk / NPR;          // 0..127 = [tensor:1][n:2][cg:4]
    int tensor = group >> 6;
    int n  = (group >> 4) & 3;
    int cg = group & 15;
    int px0 = prange * PXB;

    const float* xbase = (tensor ? predsT : predsS)
                       + (size_t)(n * CCH + cg * 16) * HW + px0;
    const float* dbase = depth + n * HW + px0;

    __shared__ short sHi[16][ROWSTR];        // 16640 B; aliased as reduce buf later
    __shared__ unsigned char sBin[PXB];      // 1 KB
    __shared__ int lhist[NB + 1];

    bool desig = (tensor == 0) && (cg == 0); // 80 blocks cover depth exactly once
    if (desig && tid < NB + 1) lhist[tid] = 0;
    __syncthreads();

    for (int i = tid; i < PXB; i += 256) {   // 4 KB coalesced depth read
        float f = dbase[i] * 64.0f;
        int b;
        if (!(f >= 0.0f) || f > 64.0f) b = NB;   // NaN via !(f>=0)
        else b = (int)f;                          // f==64.0 -> 64 (matches ref)
        sBin[i] = (unsigned char)b;
        if (desig) atomicAdd(&lhist[b], 1);
    }

    int lane = tid & 63, wv = tid >> 6;
    int l15 = lane & 15, q = lane >> 4;

    f32x4 acc[4];
    #pragma unroll
    for (int mt = 0; mt < 4; ++mt) acc[mt] = (f32x4)0.0f;

    // preload phase 0: wave wv stages rows [wv*4, wv*4+4); per row 2x 1KB instrs
    float4 vv[8];
    #pragma unroll
    for (int i = 0; i < 8; ++i) {
        int rr = i >> 1, p2 = i & 1;
        vv[i] = *(const float4*)(xbase + (size_t)(wv * 4 + rr) * HW + p2 * 256 + lane * 4);
    }

    for (int tt = 0; tt < 2; ++tt) {
        __syncthreads();   // sBin ready (tt=0) / prev MFMA done reading sHi (tt=1)
        #pragma unroll
        for (int i = 0; i < 8; ++i) {
            int rr = i >> 1, p2 = i & 1;
            unsigned u0 = __float_as_uint(vv[i].x), u1 = __float_as_uint(vv[i].y);
            unsigned u2 = __float_as_uint(vv[i].z), u3 = __float_as_uint(vv[i].w);
            uint2 hv;   // bf16 round-half-up (R5-validated precision)
            hv.x = ((u0 + 0x8000u) >> 16) | ((u1 + 0x8000u) & 0xFFFF0000u);
            hv.y = ((u2 + 0x8000u) >> 16) | ((u3 + 0x8000u) & 0xFFFF0000u);
            *(uint2*)&sHi[wv * 4 + rr][p2 * 256 + lane * 4] = hv;
        }
        if (tt == 0) {   // issue phase-1 loads now: in flight across barrier+MFMA
            #pragma unroll
            for (int i = 0; i < 8; ++i) {
                int rr = i >> 1, p2 = i & 1;
                vv[i] = *(const float4*)(xbase + (size_t)(wv * 4 + rr) * HW + 512 + p2 * 256 + lane * 4);
            }
        }
        __syncthreads();
        int pbase = tt * 512 + wv * 128;     // this wave's k-chunk (global px idx)
        #pragma unroll
        for (int ks = 0; ks < 4; ++ks) {
            unsigned long long bv = *(const unsigned long long*)&sBin[pbase + ks * 32 + q * 8];
            short8 bHi = *(const short8*)&sHi[l15][wv * 128 + ks * 32 + q * 8];
            #pragma unroll
            for (int mt = 0; mt < 4; ++mt) {
                int tgt = mt * 16 + l15;
                short8 afr;
                #pragma unroll
                for (int j = 0; j < 8; ++j)
                    afr[j] = ((int)((bv >> (8 * j)) & 0xFFull) == tgt) ? (short)0x3F80 : (short)0;
                acc[mt] = __builtin_amdgcn_mfma_f32_16x16x32_bf16(afr, bHi, acc[mt], 0, 0, 0);
            }
        }
    }

    // cross-wave reduce in LDS (alias staging buffer; 16 KB <= 16640 B)
    __syncthreads();
    float* red = (float*)&sHi[0][0];
    #pragma unroll
    for (int mt = 0; mt < 4; ++mt)
        #pragma unroll
        for (int r = 0; r < 4; ++r)
            red[wv * 1024 + (mt * 16 + q * 4 + r) * 16 + l15] = acc[mt][r];
    __syncthreads();
    float* dst = sums + (size_t)(blk & 1) * REP_STRIDE
               + (size_t)tensor * NB * CCH + cg * 16;
    #pragma unroll
    for (int k = 0; k < 4; ++k) {
        int e = tid + k * 256;               // e = bin*16 + chLocal
        float s = red[e] + red[1024 + e] + red[2048 + e] + red[3072 + e];
        atomicAdd(&dst[(e >> 4) * CCH + (e & 15)], s);
    }
    if (desig && tid < NB + 1 && lhist[tid] != 0) atomicAdd(&counts[tid], lhist[tid]);
}

// ---------------------------------------------------------------------------
// Protos: 64 blocks x 256 threads. Folds 2 sums replicas, normalizes.
__global__ __launch_bounds__(256) void k_protos(const float* __restrict__ sums,
                                                const int* __restrict__ counts,
                                                float* __restrict__ pS,
                                                float* __restrict__ pT) {
    int b = blockIdx.x, t = threadIdx.x;
    int ci = counts[b];
    float cnt = (float)(ci < 1 ? 1 : ci);
    float mS = (sums[b * CCH + t] + sums[REP_STRIDE + b * CCH + t]) / cnt;
    float mT = (sums[(NB + b) * CCH + t] + sums[REP_STRIDE + (NB + b) * CCH + t]) / cnt;
    float ss = mS * mS, st = mT * mT;
    #pragma unroll
    for (int o = 32; o; o >>= 1) {
        ss += __shfl_xor(ss, o, 64);
        st += __shfl_xor(st, o, 64);
    }
    __shared__ float rs[4], rt[4];
    int w = t >> 6;
    if ((t & 63) == 0) { rs[w] = ss; rt[w] = st; }
    __syncthreads();
    float nS = sqrtf(rs[0] + rs[1] + rs[2] + rs[3]);
    float nT = sqrtf(rt[0] + rt[1] + rt[2] + rt[3]);
    pS[b * CCH + t] = mS / fmaxf(nS, 1e-12f);
    pT[b * CCH + t] = mT / fmaxf(nT, 1e-12f);
}

// ---------------------------------------------------------------------------
// Sims + loss: 64 blocks (row i) x 256 threads. Ticketed final write.
__global__ __launch_bounds__(256) void k_sim(const float* __restrict__ pS,
                                             const float* __restrict__ pT,
                                             float* __restrict__ acc,
                                             unsigned int* __restrict__ ticket,
                                             float* __restrict__ out) {
    int i = blockIdx.x;
    int t = threadIdx.x;
    int j = t & 63, seg = t >> 6;
    __shared__ float rowS[CCH], rowT[CCH];
    rowS[t] = pS[i * CCH + t];
    rowT[t] = pT[i * CCH + t];
    __syncthreads();
    const float4* Sj = (const float4*)(pS + j * CCH + seg * 64);
    const float4* Tj = (const float4*)(pT + j * CCH + seg * 64);
    const float4* Si = (const float4*)(rowS + seg * 64);
    const float4* Ti = (const float4*)(rowT + seg * 64);
    float dS = 0.0f, dT = 0.0f;
    #pragma unroll
    for (int k = 0; k < 16; ++k) {
        float4 a = Si[k], b = Sj[k];
        dS += a.x * b.x + a.y * b.y + a.z * b.z + a.w * b.w;
        float4 c = Ti[k], d = Tj[k];
        dT += c.x * d.x + c.y * d.y + c.z * d.z + c.w * d.w;
    }
    __shared__ float sS[4][64], sT[4][64];
    sS[seg][j] = dS;
    sT[seg][j] = dT;
    __syncthreads();
    if (t < 64) {
        float fS = sS[0][t] + sS[1][t] + sS[2][t] + sS[3][t];
        float fT = sT[0][t] + sT[1][t] + sT[2][t] + sT[3][t];
        float e = fS - fT;
        e = e * e;
        #pragma unroll
        for (int o = 32; o; o >>= 1) e += __shfl_xor(e, o, 64);
        if (t == 0) {
            atomicAdd(acc, e);
            __threadfence();
            unsigned int r = atomicAdd(ticket, 1u);
            if (r == NB - 1) {
                float tot = atomicAdd(acc, 0.0f);   // device-scope read
                out[0] = tot * (1.0f / (float)(NB * NB));
            }
        }
    }
}

extern "C" void kernel_launch(void* const* d_in, const int* in_sizes, int n_in,
                              void* d_out, int out_size, void* d_ws, size_t ws_size,
                              hipStream_t stream) {
    const float* predsS = (const float*)d_in[0];
    const float* predsT = (const float*)d_in[1];
    const float* depth  = (const float*)d_in[2];
    char* ws = (char*)d_ws;
    float* sums = (float*)ws;
    int* counts = (int*)(ws + WS_COUNTS);
    float* acc = (float*)(ws + WS_ACC);
    unsigned int* ticket = (unsigned int*)(ws + WS_TICKET);
    float* pS = (float*)(ws + WS_PS);
    float* pT = (float*)(ws + WS_PT);

    hipMemsetAsync(ws, 0, WS_ZERO, stream);
    k_msum<<<GRID_MS, 256, 0, stream>>>(predsS, predsT, depth, sums, counts);
    k_protos<<<NB, 256, 0, stream>>>(sums, counts, pS, pT);
    k_sim<<<NB, 256, 0, stream>>>(pS, pT, acc, ticket, (float*)d_out);
}